// Round 4
// baseline (281.737 us; speedup 1.0000x reference)
//
#include <hip/hip_runtime.h>

#define T_DIM 2048
#define F_DIM 16
#define B_DIM 1024
#define STEPS 300

// ws layout:
//   cbuf   @ 0     : float c[j*1024 + b]   (16 KB)
//   validw @ 16384 : u64 validw[j*5 + w]   (160 B)
#define OFF_VALID 16384u

// kA: block = batch. 4 threads compute c_j (exact left-to-right sum order),
// stage feats 10..13 (t<300) in LDS, ballot per-(j,wave) valid words,
// read-then-atomicOr (skip when no new bits -> atomics collapse once mask
// saturates; monotone set-only so stale reads are safe).
__global__ void __launch_bounds__(320) kA(const float* __restrict__ x,
                                          const float* __restrict__ wptr,
                                          float* __restrict__ cbuf,
                                          unsigned long long* __restrict__ validw) {
#pragma clang fp contract(off)
    __shared__ float sF[4][STEPS];
    __shared__ float sc[4];
    int b = blockIdx.x;
    int t = threadIdx.x;
    int wv = t >> 6;  // wave 0..4 covers i in [64*wv, 64*wv+63]

    if (t < 4) {  // per-batch constants; thread t handles j = t+1
        const float* xl = x + ((size_t)b * T_DIM + (T_DIM - 1)) * F_DIM;
        float w = *wptr;
        float d = 0.0f;
        for (int k = 0; k <= t; ++k) d = d + xl[k];   // left-to-right == np.sum
        float den = w + xl[5 + t] * 25.0f;            // no FMA (contract off)
        float td  = (d * 150.0f) / den;               // IEEE div
        float c   = td * 10.0f;
        sc[t] = c;
        cbuf[t * B_DIM + b] = c;
    }
    bool act = t < STEPS;
    if (act) {
        const float* row = x + ((size_t)b * T_DIM + t) * F_DIM;
        float2 p0 = *(const float2*)(row + 10);  // feats 10,11
        float2 p1 = *(const float2*)(row + 12);  // feats 12,13
        sF[0][t] = p0.x; sF[1][t] = p0.y; sF[2][t] = p1.x; sF[3][t] = p1.y;
    }
    __syncthreads();

#pragma unroll
    for (int j = 0; j < 4; ++j) {
        bool bit = false;
        if (act) {
            float r = (float)t - sc[j];   // same f32 rounding as reference
            int idx = (int)r;             // trunc toward zero == astype(int32)
            idx = idx < 0 ? 0 : (idx > STEPS - 1 ? STEPS - 1 : idx);  // c>=0
            bit = sF[j][idx] != 0.0f;
        }
        unsigned long long m = __ballot(bit);
        if ((t & 63) == 0 && m) {
            unsigned long long cur = validw[j * 5 + wv];  // racy read: only
            if (m & ~cur) atomicOr(&validw[j * 5 + wv], m);  // extra atomics
        }
    }
}

// kC: block = batch; thread t = step i. Coalesced out writes; gathers hit the
// L2/L3-resident x[:,0:300,:] lines kA already fetched.
__global__ void __launch_bounds__(320) kC(const float* __restrict__ x,
                                          const float* __restrict__ cbuf,
                                          const unsigned long long* __restrict__ validw,
                                          float* __restrict__ out) {
#pragma clang fp contract(off)
    int b = blockIdx.x;
    int t = threadIdx.x;
    if (t >= STEPS) return;
    int wi = t >> 6, bi = t & 63;
    unsigned m = 0;
#pragma unroll
    for (int j = 0; j < 4; ++j)
        m |= (unsigned)((validw[j * 5 + wi] >> bi) & 1ull) << j;
    float r = 0.0f;
    if (m) {
        int j = __ffs(m) - 1;  // argmax of bool row == first True
        float c = cbuf[j * B_DIM + b];
        float rr = (float)t - c;
        int idx = (int)rr;
        idx = idx < 0 ? 0 : (idx > STEPS - 1 ? STEPS - 1 : idx);
        r = x[((size_t)b * T_DIM + idx) * F_DIM + 10 + j];
    }
    out[b * STEPS + t] = r;
}

extern "C" void kernel_launch(void* const* d_in, const int* in_sizes, int n_in,
                              void* d_out, int out_size, void* d_ws, size_t ws_size,
                              hipStream_t stream) {
    const float* x    = (const float*)d_in[3];
    const float* wptr = (const float*)d_in[4];
    float* out = (float*)d_out;  // (1024, 300) row-major

    float*              cbuf   = (float*)d_ws;
    unsigned long long* validw = (unsigned long long*)((char*)d_ws + OFF_VALID);

    hipMemsetAsync(validw, 0, 20 * sizeof(unsigned long long), stream);
    hipLaunchKernelGGL(kA, dim3(B_DIM), dim3(320), 0, stream, x, wptr, cbuf, validw);
    hipLaunchKernelGGL(kC, dim3(B_DIM), dim3(320), 0, stream, x, cbuf, validw, out);
}

// Round 5
// 179.753 us; speedup vs baseline: 1.5674x; 1.5674x over previous
//
#include <hip/hip_runtime.h>

#define T_DIM 2048
#define F_DIM 16
#define B_DIM 1024
#define STEPS 300

// ws layout (no init required; every word is plainly written before read):
//   cbuf    @ 0      : float c[j*1024 + b]                (16 KB)
//   partial @ 16384  : u64 partial[(j*5+w)*1024 + b]      (160 KB)
//   validw  @ 180224 : u64 validw[j*5 + w]                (160 B)
#define OFF_PARTIAL 16384u
#define OFF_VALID   180224u

// kA: block = batch. 4 threads compute c_j (left-to-right sum order), stage
// feats 10..13 (t<300) in LDS, ballot per-(j,wave) valid words, plain store
// to partial[][b]. No atomics, no contended lines.
__global__ void __launch_bounds__(320) kA(const float* __restrict__ x,
                                          const float* __restrict__ wptr,
                                          float* __restrict__ cbuf,
                                          unsigned long long* __restrict__ partial) {
#pragma clang fp contract(off)
    __shared__ float sF[4][STEPS];
    __shared__ float sc[4];
    int b = blockIdx.x;
    int t = threadIdx.x;
    int wv = t >> 6;  // wave 0..4 covers i in [64*wv, 64*wv+63]

    if (t < 4) {  // thread t handles j = t+1
        const float* xl = x + ((size_t)b * T_DIM + (T_DIM - 1)) * F_DIM;
        float w = *wptr;
        float d = 0.0f;
        for (int k = 0; k <= t; ++k) d = d + xl[k];   // left-to-right == np.sum
        float den = w + xl[5 + t] * 25.0f;            // no FMA (contract off)
        float td  = (d * 150.0f) / den;               // IEEE div
        float c   = td * 10.0f;
        sc[t] = c;
        cbuf[t * B_DIM + b] = c;
    }
    bool act = t < STEPS;
    if (act) {
        const float* row = x + ((size_t)b * T_DIM + t) * F_DIM;
        float2 p0 = *(const float2*)(row + 10);  // feats 10,11
        float2 p1 = *(const float2*)(row + 12);  // feats 12,13
        sF[0][t] = p0.x; sF[1][t] = p0.y; sF[2][t] = p1.x; sF[3][t] = p1.y;
    }
    __syncthreads();

#pragma unroll
    for (int j = 0; j < 4; ++j) {
        bool bit = false;
        if (act) {
            float r = (float)t - sc[j];   // same f32 rounding as reference
            int idx = (int)r;             // trunc toward zero == astype(int32)
            idx = idx < 0 ? 0 : (idx > STEPS - 1 ? STEPS - 1 : idx);  // c>=0
            bit = sF[j][idx] != 0.0f;
        }
        unsigned long long m = __ballot(bit);
        if ((t & 63) == 0)
            partial[(size_t)(j * 5 + wv) * B_DIM + b] = m;  // plain store
    }
}

// kB: block k OR-reduces partial[k][0..1024) -> validw[k]. Coalesced reads,
// shfl-OR within wave, LDS tree across the 4 waves.
__global__ void __launch_bounds__(256) kB(const unsigned long long* __restrict__ partial,
                                          unsigned long long* __restrict__ validw) {
    __shared__ unsigned long long sred[4];
    int k = blockIdx.x;          // word index 0..19
    int t = threadIdx.x;
    const unsigned long long* p = partial + (size_t)k * B_DIM;
    unsigned long long a = p[t] | p[t + 256] | p[t + 512] | p[t + 768];
    unsigned lo = (unsigned)a, hi = (unsigned)(a >> 32);
#pragma unroll
    for (int s = 32; s; s >>= 1) {
        lo |= __shfl_xor(lo, s, 64);
        hi |= __shfl_xor(hi, s, 64);
    }
    if ((t & 63) == 0) sred[t >> 6] = ((unsigned long long)hi << 32) | lo;
    __syncthreads();
    if (t == 0) validw[k] = sred[0] | sred[1] | sred[2] | sred[3];
}

// kC: block = batch; thread t = step i. Coalesced out writes; gathers hit the
// L2/L3-resident x[:,0:300,:] lines kA already fetched. validw is plain data.
__global__ void __launch_bounds__(320) kC(const float* __restrict__ x,
                                          const float* __restrict__ cbuf,
                                          const unsigned long long* __restrict__ validw,
                                          float* __restrict__ out) {
#pragma clang fp contract(off)
    int b = blockIdx.x;
    int t = threadIdx.x;
    if (t >= STEPS) return;
    int wi = t >> 6, bi = t & 63;
    unsigned m = 0;
#pragma unroll
    for (int j = 0; j < 4; ++j)
        m |= (unsigned)((validw[j * 5 + wi] >> bi) & 1ull) << j;
    float r = 0.0f;
    if (m) {
        int j = __ffs(m) - 1;  // argmax of bool row == first True
        float c = cbuf[j * B_DIM + b];
        float rr = (float)t - c;
        int idx = (int)rr;
        idx = idx < 0 ? 0 : (idx > STEPS - 1 ? STEPS - 1 : idx);
        r = x[((size_t)b * T_DIM + idx) * F_DIM + 10 + j];
    }
    out[b * STEPS + t] = r;
}

extern "C" void kernel_launch(void* const* d_in, const int* in_sizes, int n_in,
                              void* d_out, int out_size, void* d_ws, size_t ws_size,
                              hipStream_t stream) {
    const float* x    = (const float*)d_in[3];
    const float* wptr = (const float*)d_in[4];
    float* out = (float*)d_out;  // (1024, 300) row-major

    float*              cbuf    = (float*)d_ws;
    unsigned long long* partial = (unsigned long long*)((char*)d_ws + OFF_PARTIAL);
    unsigned long long* validw  = (unsigned long long*)((char*)d_ws + OFF_VALID);

    hipLaunchKernelGGL(kA, dim3(B_DIM), dim3(320), 0, stream, x, wptr, cbuf, partial);
    hipLaunchKernelGGL(kB, dim3(20), dim3(256), 0, stream, partial, validw);
    hipLaunchKernelGGL(kC, dim3(B_DIM), dim3(320), 0, stream, x, cbuf, validw, out);
}